// Round 11
// baseline (509.613 us; speedup 1.0000x reference)
//
#include <hip/hip_runtime.h>
#include <math.h>

#define NROW 8192
#define DDIM 128
#define CAP 16384
#define NDIAG 8192       // entries [0,NDIAG) are the implicit diagonal (i==j==e)
#define NITERS 100
#define NWARM 6
#define AC (1.0f / 8192.0f)
#define JTPB 4           // j-tiles (128 cols each) per scan block

struct Entry { int i, j; float s, t; };

// ws layout (bytes):
// 0       : x2   float[NROW]
// 32768   : y2   float[NROW]
// 65536   : x2h  float[NROW]     partial (32-dim) norms
// 98304   : y2h  float[NROW]
// 131072  : counts int[8]        { [0..2]=list counts (start NDIAG), [3..5]=off-diag active, [6]=epi done-counter }
// 131104  : minx64 uint[128]     per-64-row min of x2h
// 131616  : miny64 uint[128]
// 132128  : accum double[3][264] { [0..4]=Su,Sv,Sux2,Svy2,Ssp [5]=R [6]=bu [7]=bv [8..135]=P [136..263]=Q }
// 138464  : lists Entry[3][CAP]  (slots [0,NDIAG) implicit diagonal; scan appends at >=NDIAG)
// 924896  : X32 ushort[NROW*32]  bf16 of first 32 dims
// 1449184 : Y32 ushort[NROW*32]
// 1973472 : sdiag float[3][NROW]
// 2071776 : tdiag float[3][NROW]
// 2170080 : u_g  float[3][NROW]
// 2268384 : v_g  float[3][NROW]  -> total 2366688

typedef __attribute__((ext_vector_type(8))) short frag_ab;   // 8 bf16
typedef __attribute__((ext_vector_type(4))) float frag_cd;   // 4 fp32

__device__ inline unsigned short f2bf(float f) {
    unsigned u = __float_as_uint(f);
    return (unsigned short)((u + 0x7FFFu + ((u >> 16) & 1u)) >> 16);  // RN-even
}

#define ALD(p) __hip_atomic_load((p), __ATOMIC_RELAXED, __HIP_MEMORY_SCOPE_AGENT)

// norms + partial norms + bf16 compaction + per-64-row minima + ALL diagonal
// s/t values (XY via computed dot; XX/YY analytically C=0) + init. 128 blocks.
__global__ __launch_bounds__(256) void norms3_k(const float* __restrict__ X,
                                                const float* __restrict__ Y,
                                                float* __restrict__ x2, float* __restrict__ y2,
                                                float* __restrict__ x2h, float* __restrict__ y2h,
                                                unsigned* __restrict__ minx64,
                                                unsigned* __restrict__ miny64,
                                                unsigned short* __restrict__ X32,
                                                unsigned short* __restrict__ Y32,
                                                float* __restrict__ sdiag,
                                                float* __restrict__ tdiag,
                                                int* counts, double* accum) {
    int b = blockIdx.x;                       // 64 rows per block
    int t = threadIdx.x, w = t >> 6, lane = t & 63;
    float mnx = 1e30f, mny = 1e30f;
    int r0 = b * 64 + w * 16;
    for (int k = 0; k < 16; k++) {
        int r = r0 + k;
        float2 vx = *(const float2*)(X + (size_t)r * DDIM + lane * 2);
        float2 vy = *(const float2*)(Y + (size_t)r * DDIM + lane * 2);
        if (lane < 16) {
            *(unsigned*)(X32 + (size_t)r * 32 + lane * 2) =
                (unsigned)f2bf(vx.x) | ((unsigned)f2bf(vx.y) << 16);
            *(unsigned*)(Y32 + (size_t)r * 32 + lane * 2) =
                (unsigned)f2bf(vy.x) | ((unsigned)f2bf(vy.y) << 16);
        }
        float sx = vx.x * vx.x + vx.y * vx.y;
        float sy = vy.x * vy.x + vy.y * vy.y;
        float dt = vx.x * vy.x + vx.y * vy.y;
        float phx = (lane < 16) ? sx : 0.f;
        float phy = (lane < 16) ? sy : 0.f;
        for (int o = 32; o; o >>= 1) {
            sx += __shfl_down(sx, o, 64); sy += __shfl_down(sy, o, 64);
            dt += __shfl_down(dt, o, 64);
            phx += __shfl_down(phx, o, 64); phy += __shfl_down(phy, o, 64);
        }
        if (lane == 0) {
            x2[r] = sx; y2[r] = sy; x2h[r] = phx; y2h[r] = phy;
            mnx = fminf(mnx, phx); mny = fminf(mny, phy);
            // p=0 (XY) diagonal: exact C(x_r, y_r)
            float raw = sx + sy - 2.f * dt;
            float C = fmaxf(raw, 0.f);
            float sc = fmaxf(-100.f * C, -50.f);
            float K = fmaxf(expf(sc), 1e-8f);
            float s0 = K - 1e-8f;
            sdiag[r] = s0;
            tdiag[r] = (raw >= 0.f) ? s0 * C : (-1e-8f) * raw;
            // p=1 (XX), p=2 (YY): C_ii = 0 -> K = 1
            sdiag[NROW + r] = 1.f - 1e-8f;     tdiag[NROW + r] = 0.f;
            sdiag[2 * NROW + r] = 1.f - 1e-8f; tdiag[2 * NROW + r] = 0.f;
        }
    }
    __shared__ float mrx[4], mry[4];
    if (lane == 0) { mrx[w] = mnx; mry[w] = mny; }
    __syncthreads();
    if (t == 0) {
        minx64[b] = __float_as_uint(fminf(fminf(mrx[0], mrx[1]), fminf(mrx[2], mrx[3])));
        miny64[b] = __float_as_uint(fminf(fminf(mry[0], mry[1]), fminf(mry[2], mry[3])));
    }
    if (b == 0) {
        if (t < 3) counts[t] = NDIAG;
        else if (t < 8) counts[t] = 0;
        for (int i = t; i < 3 * 264; i += 256) accum[i] = 0.0;
    }
}

// LDS-staged 32-dim MFMA prescan, 128x512 region per block, inline exact for
// off-diag candidates. C32 = x2h[i]+y2h[j]-2*dot32 is an exact lower bound on C.
__global__ __launch_bounds__(256) void scan6_k(const unsigned short* __restrict__ X32,
                                               const unsigned short* __restrict__ Y32,
                                               const float* __restrict__ Xf,
                                               const float* __restrict__ Yf,
                                               const float* __restrict__ x2h,
                                               const float* __restrict__ y2h,
                                               const float* __restrict__ x2,
                                               const float* __restrict__ y2,
                                               const unsigned* __restrict__ minx64,
                                               const unsigned* __restrict__ miny64,
                                               int* counts, Entry* lists, int* rescnt) {
    int p = blockIdx.z, bx = blockIdx.x;
    int jt0 = blockIdx.y * JTPB;
    if (p && jt0 + JTPB <= bx) return;        // symmetric pairs: chunk fully below diagonal
    const unsigned short* Ab = (p == 2) ? Y32 : X32;
    const unsigned short* Bb = (p == 0) ? Y32 : ((p == 1) ? X32 : Y32);
    const float* Af = (p == 2) ? Yf : Xf;
    const float* Bf = (p == 0) ? Yf : ((p == 1) ? Xf : Yf);
    const float* nah = (p == 2) ? y2h : x2h;
    const float* nbh = (p == 0) ? y2h : ((p == 1) ? x2h : y2h);
    const float* naf = (p == 2) ? y2 : x2;
    const float* nbf = (p == 0) ? y2 : ((p == 1) ? x2 : y2);
    const unsigned* mA64 = (p == 2) ? miny64 : minx64;
    const unsigned* mB64 = (p == 0) ? miny64 : ((p == 1) ? minx64 : miny64);
    int i0 = bx * 128;
    int t = threadIdx.x;

    __shared__ uint4 As[512];        // 8 KB  (128 rows x 4 units of 16B)
    __shared__ uint4 Bs[JTPB][512];  // 32 KB
    {
        const uint4* ga = (const uint4*)(Ab + (size_t)i0 * 32);
        As[t] = ga[t]; As[t + 256] = ga[t + 256];
        for (int jt = 0; jt < JTPB; jt++) {
            int jtt = jt0 + jt;
            if (p && jtt < bx) continue;
            const uint4* gb = (const uint4*)(Bb + (size_t)jtt * 128 * 32);
            Bs[jt][t] = gb[t]; Bs[jt][t + 256] = gb[t + 256];
        }
    }
    __syncthreads();

    int w = t >> 6, lane = t & 63, lm = lane & 15, quad = lane >> 4;
    int wr = (w & 1) * 64;
    frag_ab a[4];
    #pragma unroll
    for (int rt = 0; rt < 4; rt++)
        a[rt] = *(const frag_ab*)&As[(wr + rt * 16 + lm) * 4 + quad];
    float mA = fminf(__uint_as_float(mA64[2 * bx]), __uint_as_float(mA64[2 * bx + 1]));
    Entry* list = lists + (size_t)p * CAP;

    #pragma unroll
    for (int kk = 0; kk < 4; kk++) {
        int c64 = (w >> 1) + 2 * kk;          // 0..7 column-64 within the 512-col chunk
        int jt = c64 >> 1;
        int jtt = jt0 + jt;
        if (p && jtt < bx) continue;
        int jbase = jtt * 128 + (c64 & 1) * 64;
        frag_ab bf[4];
        #pragma unroll
        for (int ct = 0; ct < 4; ct++)
            bf[ct] = *(const frag_ab*)&Bs[jt][((c64 & 1) * 64 + ct * 16 + lm) * 4 + quad];
        frag_cd acc[4][4];
        #pragma unroll
        for (int rt = 0; rt < 4; rt++)
            #pragma unroll
            for (int ct = 0; ct < 4; ct++)
                acc[rt][ct] = __builtin_amdgcn_mfma_f32_16x16x32_bf16(a[rt], bf[ct],
                              (frag_cd){0.f, 0.f, 0.f, 0.f}, 0, 0, 0);
        float mB = fminf(__uint_as_float(mB64[2 * jtt]), __uint_as_float(mB64[2 * jtt + 1]));
        float thr = 0.5f * (mA + mB - 2.0f);
        #pragma unroll
        for (int rt = 0; rt < 4; rt++) {
            #pragma unroll
            for (int ct = 0; ct < 4; ct++) {
                frag_cd A4 = acc[rt][ct];
                float m4 = fmaxf(fmaxf(A4[0], A4[1]), fmaxf(A4[2], A4[3]));
                if (__any(m4 > thr)) {
                    int j = jbase + ct * 16 + lm;
                    float yjh = nbh[j];
                    #pragma unroll
                    for (int reg = 0; reg < 4; reg++) {
                        int i = i0 + wr + rt * 16 + quad * 4 + reg;
                        float Ct = nah[i] + yjh - 2.f * A4[reg];
                        if (Ct < 2.0f && i != j && (p == 0 || i < j)) {
                            // inline exact 128-dim fp32 distance (rare, divergent)
                            const float* ar = Af + (size_t)i * DDIM;
                            const float* br = Bf + (size_t)j * DDIM;
                            float dot = 0.f;
                            for (int d = 0; d < DDIM; d += 4) {
                                float4 av = *(const float4*)(ar + d);
                                float4 bv = *(const float4*)(br + d);
                                dot += av.x * bv.x + av.y * bv.y + av.z * bv.z + av.w * bv.w;
                            }
                            float raw = naf[i] + nbf[j] - 2.f * dot;
                            float C = fmaxf(raw, 0.f);
                            float sc = fmaxf(-100.f * C, -50.f);
                            float K = fmaxf(expf(sc), 1e-8f);
                            float s = K - 1e-8f;
                            float tt = (raw >= 0.f) ? s * C : (-1e-8f) * raw;
                            if (p == 0) {
                                int idx = atomicAdd(&counts[0], 1);
                                if (idx < CAP) { Entry e; e.i = i; e.j = j; e.s = s; e.t = tt; list[idx] = e; }
                            } else {
                                int idx = atomicAdd(&counts[p], 2);
                                if (idx < CAP) { Entry e; e.i = i; e.j = j; e.s = s; e.t = tt; list[idx] = e; }
                                if (idx + 1 < CAP) { Entry e; e.i = j; e.j = i; e.s = s; e.t = tt; list[idx + 1] = e; }
                            }
                            if (s != 0.f || tt != 0.f) atomicAdd(&rescnt[p], (p == 0) ? 1 : 2);
                        }
                    }
                }
            }
        }
    }
}

// Warm Sinkhorn: NWARM exact coupled iterations, then freeze bases (sub-ulp drift);
// bit-exact early exit (period 1/2, parity-corrected) -> R=0. Fallback: full scatter.
__global__ __launch_bounds__(1024, 1) void sink2_k(const int* counts,
                                                   const Entry* __restrict__ lists,
                                                   const float* __restrict__ sdiag,
                                                   float* __restrict__ u_g,
                                                   float* __restrict__ v_g,
                                                   double* accum) {
    int p = blockIdx.x;
    const Entry* list = lists + (size_t)p * CAP;
    int cnt = counts[p]; if (cnt > CAP) cnt = CAP;
    int nres = counts[3 + p];
    double* acc = accum + (size_t)p * 264;
    float* up = u_g + (size_t)p * NROW;
    float* vp = v_g + (size_t)p * NROW;

    __shared__ float u_s[NROW];   // fallback only
    __shared__ float v_s[NROW];
    __shared__ float redS[2][16];
    __shared__ unsigned redC[16];
    int t = threadIdx.x;
    int wid = t >> 6, lane = t & 63;

    if (nres == 0) {
        float vk[8], uk[8], sk[8];
        unsigned pv2[8];
        #pragma unroll
        for (int k = 0; k < 8; k++) {
            sk[k] = sdiag[p * NROW + t + 1024 * k];
            vk[k] = 1.0f; uk[k] = AC; pv2[k] = 0xFFFFFFFFu;
        }
        unsigned flags = 3u;
        int par = 0, last = 0, done = 0;
        float bu_last = 0.f;
        for (int it = 0; it < NWARM; it++) {
            float s = 0.f;
            #pragma unroll
            for (int k = 0; k < 8; k++) s += vk[k];
            for (int o = 32; o; o >>= 1) s += __shfl_down(s, o, 64);
            if (lane == 0) { redS[par][wid] = s; redC[wid] = flags; }
            __syncthreads();
            float sumv = 0.f; unsigned anyf = 0;
            #pragma unroll
            for (int w2 = 0; w2 < 16; w2++) { sumv += redS[par][w2]; anyf |= redC[w2]; }
            par ^= 1;
            if (it > 0) {
                if (!(anyf & 1)) { done = 1; break; }
                if (!(anyf & 2)) {
                    if (((NITERS - it) & 1) == 0) { done = 1; break; }
                    last = 1;
                }
            }
            float base = 1e-8f * sumv;
            #pragma unroll
            for (int k = 0; k < 8; k++) {
                float kv = fmaxf(base + sk[k] * vk[k], 1e-8f);
                uk[k] = AC * __builtin_amdgcn_rcpf(kv);
            }
            s = 0.f;
            #pragma unroll
            for (int k = 0; k < 8; k++) s += uk[k];
            for (int o = 32; o; o >>= 1) s += __shfl_down(s, o, 64);
            if (lane == 0) redS[par][wid] = s;
            __syncthreads();
            float sumu = 0.f;
            #pragma unroll
            for (int w2 = 0; w2 < 16; w2++) sumu += redS[par][w2];
            par ^= 1;
            base = 1e-8f * sumu;
            bu_last = base;
            unsigned d1 = 0, d2 = 0;
            #pragma unroll
            for (int k = 0; k < 8; k++) {
                float kv = fmaxf(base + sk[k] * uk[k], 1e-8f);
                float nv = AC * __builtin_amdgcn_rcpf(kv);
                unsigned nb_ = __float_as_uint(nv);
                d1 |= nb_ ^ __float_as_uint(vk[k]);
                d2 |= nb_ ^ pv2[k];
                pv2[k] = __float_as_uint(vk[k]);
                vk[k] = nv;
            }
            flags = (__any(d1 != 0) ? 1u : 0u) | (__any(d2 != 0) ? 2u : 0u);
            if (last) { done = 1; break; }
        }
        float bv_f = 0.f;
        int R = 0;
        if (!done) {
            float s = 0.f;
            #pragma unroll
            for (int k = 0; k < 8; k++) s += vk[k];
            for (int o = 32; o; o >>= 1) s += __shfl_down(s, o, 64);
            if (lane == 0) redS[par][wid] = s;
            __syncthreads();
            float sumv = 0.f;
            #pragma unroll
            for (int w2 = 0; w2 < 16; w2++) sumv += redS[par][w2];
            bv_f = 1e-8f * sumv;
            R = NITERS - NWARM;
        }
        #pragma unroll
        for (int k = 0; k < 8; k++) {
            int i = t + 1024 * k;
            up[i] = uk[k]; vp[i] = vk[k];
        }
        if (t == 0) { acc[5] = (double)R; acc[6] = (double)bu_last; acc[7] = (double)bv_f; }
    } else {
        // fallback: general sparse scatter (implicit diag + list), full 100 iterations
        for (int i = t; i < NROW; i += 1024) { u_s[i] = 1.0f; v_s[i] = 1.0f; }
        __syncthreads();
        for (int it = 0; it < NITERS; it++) {
            {
                float sv = 0.f;
                for (int i = t; i < NROW; i += 1024) sv += v_s[i];
                for (int o = 32; o; o >>= 1) sv += __shfl_down(sv, o, 64);
                if (lane == 0) u_s[wid] = sv;
                __syncthreads();
                if (t < 64) {
                    float s2 = (t < 16) ? u_s[t] : 0.f;
                    for (int o = 8; o; o >>= 1) s2 += __shfl_down(s2, o, 64);
                    if (t == 0) u_s[0] = s2;
                }
                __syncthreads();
                float sum_v = u_s[0];
                __syncthreads();
                for (int i = t; i < NROW; i += 1024) u_s[i] = 1e-8f * sum_v;
                __syncthreads();
                for (int e = t; e < cnt; e += 1024) {
                    int ei, ej; float es;
                    if (e < NDIAG) { ei = e; ej = e; es = sdiag[p * NROW + e]; }
                    else { ei = list[e].i; ej = list[e].j; es = list[e].s; }
                    atomicAdd(&u_s[ei], es * v_s[ej]);
                }
                __syncthreads();
                for (int i = t; i < NROW; i += 1024) u_s[i] = AC / fmaxf(u_s[i], 1e-8f);
                __syncthreads();
            }
            {
                float su = 0.f;
                for (int i = t; i < NROW; i += 1024) su += u_s[i];
                for (int o = 32; o; o >>= 1) su += __shfl_down(su, o, 64);
                if (lane == 0) v_s[wid] = su;
                __syncthreads();
                if (t < 64) {
                    float s2 = (t < 16) ? v_s[t] : 0.f;
                    for (int o = 8; o; o >>= 1) s2 += __shfl_down(s2, o, 64);
                    if (t == 0) v_s[0] = s2;
                }
                __syncthreads();
                float sum_u = v_s[0];
                __syncthreads();
                for (int i = t; i < NROW; i += 1024) v_s[i] = 1e-8f * sum_u;
                __syncthreads();
                for (int e = t; e < cnt; e += 1024) {
                    int ei, ej; float es;
                    if (e < NDIAG) { ei = e; ej = e; es = sdiag[p * NROW + e]; }
                    else { ei = list[e].i; ej = list[e].j; es = list[e].s; }
                    atomicAdd(&v_s[ej], es * u_s[ei]);
                }
                __syncthreads();
                for (int i = t; i < NROW; i += 1024) v_s[i] = AC / fmaxf(v_s[i], 1e-8f);
                __syncthreads();
            }
        }
        for (int i = t; i < NROW; i += 1024) { up[i] = u_s[i]; vp[i] = v_s[i]; }
        if (t == 0) { acc[5] = 0.0; acc[6] = 0.0; acc[7] = 0.0; }
    }
}

// fused epilogue + last-block combine. 64 blocks x 128 rows. Frozen-base iters
// per pair, scalar sums, P/Q with X,Y each read once; last block (device-fence +
// agent-scope atomic loads) does sparse correction + final divergence.
__global__ __launch_bounds__(256) void epi3_k(const float* __restrict__ X,
                                              const float* __restrict__ Y,
                                              const float* __restrict__ x2,
                                              const float* __restrict__ y2,
                                              const float* __restrict__ u_g,
                                              const float* __restrict__ v_g,
                                              const float* __restrict__ sdiag,
                                              const float* __restrict__ tdiag,
                                              int* counts, const Entry* __restrict__ lists,
                                              double* accum, float* __restrict__ out) {
    int t = threadIdx.x, lane = t & 63;
    int rbase = blockIdx.x * 128;
    __shared__ float uf[3][128], vf[3][128];
    if (t < 128) {
        int r = rbase + t;
        for (int p = 0; p < 3; p++) {
            double* acc = accum + (size_t)p * 264;
            int R = (int)acc[5];
            float bu = (float)acc[6], bv = (float)acc[7];
            float s = sdiag[p * NROW + r];
            float u = u_g[p * NROW + r], v = v_g[p * NROW + r];
            for (int k = 0; k < R; k++) {
                u = AC * __builtin_amdgcn_rcpf(fmaxf(bv + s * v, 1e-8f));
                v = AC * __builtin_amdgcn_rcpf(fmaxf(bu + s * u, 1e-8f));
            }
            uf[p][t] = u; vf[p][t] = v;
            const float* na = (p == 2) ? y2 : x2;
            const float* nb = (p == 0) ? y2 : ((p == 1) ? x2 : y2);
            double a0 = u, a1 = v, a2 = (double)u * na[r], a3 = (double)v * nb[r];
            double a4 = (double)u * (double)v * (double)tdiag[p * NROW + r];
            for (int o = 32; o; o >>= 1) {
                a0 += __shfl_down(a0, o, 64); a1 += __shfl_down(a1, o, 64);
                a2 += __shfl_down(a2, o, 64); a3 += __shfl_down(a3, o, 64);
                a4 += __shfl_down(a4, o, 64);
            }
            if (lane == 0) {
                atomicAdd(&acc[0], a0); atomicAdd(&acc[1], a1);
                atomicAdd(&acc[2], a2); atomicAdd(&acc[3], a3);
                atomicAdd(&acc[4], a4);
            }
        }
    }
    __syncthreads();
    int dq = (t & 31) * 4, g = t >> 5;   // 8 row-groups x 16 iters = 128 rows
    {   // X pass: u0 -> P0, u1 -> P1, v1 -> Q1
        double s0[4] = {0,0,0,0}, s1[4] = {0,0,0,0}, s2[4] = {0,0,0,0};
        for (int k = 0; k < 16; k++) {
            int lr = g + 8 * k, rr = rbase + lr;
            float4 xv = *(const float4*)(X + (size_t)rr * DDIM + dq);
            double w0 = uf[0][lr], w1 = uf[1][lr], w2 = vf[1][lr];
            s0[0] += w0 * xv.x; s0[1] += w0 * xv.y; s0[2] += w0 * xv.z; s0[3] += w0 * xv.w;
            s1[0] += w1 * xv.x; s1[1] += w1 * xv.y; s1[2] += w1 * xv.z; s1[3] += w1 * xv.w;
            s2[0] += w2 * xv.x; s2[1] += w2 * xv.y; s2[2] += w2 * xv.z; s2[3] += w2 * xv.w;
        }
        #pragma unroll
        for (int m = 0; m < 4; m++) {
            atomicAdd(&accum[0 * 264 + 8 + dq + m], s0[m]);
            atomicAdd(&accum[1 * 264 + 8 + dq + m], s1[m]);
            atomicAdd(&accum[1 * 264 + 136 + dq + m], s2[m]);
        }
    }
    {   // Y pass: v0 -> Q0, u2 -> P2, v2 -> Q2
        double s0[4] = {0,0,0,0}, s1[4] = {0,0,0,0}, s2[4] = {0,0,0,0};
        for (int k = 0; k < 16; k++) {
            int lr = g + 8 * k, rr = rbase + lr;
            float4 yv = *(const float4*)(Y + (size_t)rr * DDIM + dq);
            double w0 = vf[0][lr], w1 = uf[2][lr], w2 = vf[2][lr];
            s0[0] += w0 * yv.x; s0[1] += w0 * yv.y; s0[2] += w0 * yv.z; s0[3] += w0 * yv.w;
            s1[0] += w1 * yv.x; s1[1] += w1 * yv.y; s1[2] += w1 * yv.z; s1[3] += w1 * yv.w;
            s2[0] += w2 * yv.x; s2[1] += w2 * yv.y; s2[2] += w2 * yv.z; s2[3] += w2 * yv.w;
        }
        #pragma unroll
        for (int m = 0; m < 4; m++) {
            atomicAdd(&accum[0 * 264 + 136 + dq + m], s0[m]);
            atomicAdd(&accum[2 * 264 + 8 + dq + m], s1[m]);
            atomicAdd(&accum[2 * 264 + 136 + dq + m], s2[m]);
        }
    }
    // ---- last-block combine ----
    __shared__ int isLast;
    __threadfence();
    if (t == 0) isLast = (atomicAdd(&counts[6], 1) == gridDim.x - 1);
    __syncthreads();
    if (!isLast) return;
    __threadfence();
    __shared__ double red[3][4];
    __shared__ double costs[3];
    int wv = t >> 6;
    for (int p = 0; p < 3; p++) {
        int cnt = counts[p]; if (cnt > CAP) cnt = CAP;
        const Entry* list = lists + (size_t)p * CAP;
        const float* up = u_g + (size_t)p * NROW;
        const float* vp = v_g + (size_t)p * NROW;
        double sp = 0.0;
        for (int e = NDIAG + t; e < cnt; e += 256) {
            Entry en = list[e];
            if (en.t != 0.f) sp += (double)up[en.i] * (double)vp[en.j] * (double)en.t;
        }
        for (int o = 32; o; o >>= 1) sp += __shfl_down(sp, o, 64);
        if (lane == 0) red[p][wv] = sp;
    }
    __syncthreads();
    if (t < 64) {
        for (int p = 0; p < 3; p++) {
            const double* acc = accum + (size_t)p * 264;
            double part = ALD(&acc[8 + t]) * ALD(&acc[136 + t])
                        + ALD(&acc[72 + t]) * ALD(&acc[200 + t]);
            for (int o = 32; o; o >>= 1) part += __shfl_down(part, o, 64);
            if (t == 0) {
                double spo = red[p][0] + red[p][1] + red[p][2] + red[p][3];
                double F = ALD(&acc[2]) * ALD(&acc[1]) + ALD(&acc[0]) * ALD(&acc[3]) - 2.0 * part;
                double c = 1e-8 * F + ALD(&acc[4]) + spo;
                costs[p] = (c > 0.0) ? c : 0.0;
            }
        }
        if (t == 0) {
            double dv = costs[0] - 0.5 * (costs[1] + costs[2]);
            dv = fmin(fmax(dv, 0.0), 10000.0);
            out[0] = (float)dv;
        }
    }
}

extern "C" void kernel_launch(void* const* d_in, const int* in_sizes, int n_in,
                              void* d_out, int out_size, void* d_ws, size_t ws_size,
                              hipStream_t stream) {
    const float* X = (const float*)d_in[0];
    const float* Y = (const float*)d_in[1];
    float* out = (float*)d_out;
    char* ws = (char*)d_ws;
    float* x2 = (float*)ws;
    float* y2 = (float*)(ws + 32768);
    float* x2h = (float*)(ws + 65536);
    float* y2h = (float*)(ws + 98304);
    int* counts = (int*)(ws + 131072);
    unsigned* minx64 = (unsigned*)(ws + 131104);
    unsigned* miny64 = (unsigned*)(ws + 131616);
    double* accum = (double*)(ws + 132128);
    Entry* lists = (Entry*)(ws + 138464);
    unsigned short* X32 = (unsigned short*)(ws + 924896);
    unsigned short* Y32 = (unsigned short*)(ws + 1449184);
    float* sdiag = (float*)(ws + 1973472);
    float* tdiag = (float*)(ws + 2071776);
    float* u_g = (float*)(ws + 2170080);
    float* v_g = (float*)(ws + 2268384);

    norms3_k<<<128, 256, 0, stream>>>(X, Y, x2, y2, x2h, y2h, minx64, miny64,
                                      X32, Y32, sdiag, tdiag, counts, accum);
    scan6_k<<<dim3(64, 16, 3), 256, 0, stream>>>(X32, Y32, X, Y, x2h, y2h, x2, y2,
                                                 minx64, miny64, counts, lists, counts + 3);
    sink2_k<<<3, 1024, 0, stream>>>(counts, lists, sdiag, u_g, v_g, accum);
    epi3_k<<<64, 256, 0, stream>>>(X, Y, x2, y2, u_g, v_g, sdiag, tdiag,
                                   counts, lists, accum, out);
}